// Round 7
// baseline (499.101 us; speedup 1.0000x reference)
//
#include <hip/hip_runtime.h>
#include <hip/hip_bf16.h>
#include <hip/hip_cooperative_groups.h>
#include <math.h>

namespace cg = cooperative_groups;

#define BB 8
#define NN 2048
#define DD 1024
#define LL 128
#define MM (BB*NN)   // 16384

typedef __attribute__((ext_vector_type(8))) short short8;
typedef __attribute__((ext_vector_type(8))) unsigned short ushort8;
typedef __attribute__((ext_vector_type(4))) float floatx4;

__device__ __forceinline__ void glds16(const void* g, void* l) {
    __builtin_amdgcn_global_load_lds(
        (const __attribute__((address_space(1))) unsigned int*)g,
        (__attribute__((address_space(3))) unsigned int*)l, 16, 0, 0);
}

// fp32 -> bf16 hi/lo split (RNE) of 8 consecutive elements at index i*8
__device__ __forceinline__ void split8(const float* __restrict__ x,
                                       unsigned short* __restrict__ hi,
                                       unsigned short* __restrict__ lo, int i) {
    const float4* xp = (const float4*)x + (size_t)i * 2;
    float4 v0 = xp[0], v1 = xp[1];
    float f[8] = {v0.x, v0.y, v0.z, v0.w, v1.x, v1.y, v1.z, v1.w};
    ushort8 h, l;
    #pragma unroll
    for (int e = 0; e < 8; ++e) {
        unsigned u = __float_as_uint(f[e]);
        unsigned r = u + 0x7FFFu + ((u >> 16) & 1u);
        unsigned short hb = (unsigned short)(r >> 16);
        float hf = __uint_as_float((unsigned)hb << 16);
        float res = f[e] - hf;
        unsigned u2 = __float_as_uint(res);
        unsigned r2 = u2 + 0x7FFFu + ((u2 >> 16) & 1u);
        h[e] = hb;
        l[e] = (unsigned short)(r2 >> 16);
    }
    *(ushort8*)(hi + (size_t)i * 8) = h;
    *(ushort8*)(lo + (size_t)i * 8) = l;
}

// ---------------- fused preprocessing: split(e_j), split(Wk), q = e_i @ Wq^T
__global__ __launch_bounds__(256) void prep_kernel(const float* __restrict__ e_j,
                                                   unsigned short* __restrict__ ehi,
                                                   unsigned short* __restrict__ elo,
                                                   const float* __restrict__ Wk,
                                                   unsigned short* __restrict__ wh,
                                                   unsigned short* __restrict__ wl,
                                                   const float* __restrict__ e_i,
                                                   const float* __restrict__ Wq,
                                                   float* __restrict__ q) {
    int blk = blockIdx.x;
    int tid = threadIdx.x;
    if (blk < 8192) {
        split8(e_j, ehi, elo, blk * 256 + tid);
    } else if (blk < 8704) {
        split8(Wk, wh, wl, (blk - 8192) * 256 + tid);
    } else {
        int wid  = ((blk - 8704) * 256 + tid) >> 6;   // 0..8191
        int lane = tid & 63;
        int r = wid >> 10;
        int d = wid & (DD - 1);
        const float* x = e_i + (size_t)r * DD;
        const float* w = Wq + (size_t)d * DD;
        float s = 0.f;
        #pragma unroll
        for (int e0 = 0; e0 < DD; e0 += 256) {
            float4 xv = *(const float4*)&x[e0 + lane * 4];
            float4 wv = *(const float4*)&w[e0 + lane * 4];
            s += xv.x * wv.x + xv.y * wv.y + xv.z * wv.z + xv.w * wv.w;
        }
        #pragma unroll
        for (int off = 32; off; off >>= 1) s += __shfl_down(s, off, 64);
        if (lane == 0) q[wid] = s;
    }
}

// ---------------- heavy kernel: bf16x3 MFMA GEMM + fused tanh(q+k)*omega row-reduce
// (R2 version verbatim — measured 123-126 us; m97-plateau structure, leave alone.)
__global__ __launch_bounds__(256) void sigma_mfma(const unsigned short* __restrict__ ehi,
                                                  const unsigned short* __restrict__ elo,
                                                  const unsigned short* __restrict__ wh,
                                                  const unsigned short* __restrict__ wl,
                                                  const float* __restrict__ q,
                                                  const float* __restrict__ omega,
                                                  float* __restrict__ sig_part)   // [8][MM]
{
    __shared__ unsigned short lds[4][128][32];
    __shared__ float red[128][2];

    const int tid  = threadIdx.x;
    const int lane = tid & 63;
    const int w    = tid >> 6;
    const int wr   = w >> 1, wc = w & 1;
    const int c15  = lane & 15, quad = lane >> 4;

    const int row0 = blockIdx.x * 128;
    const int col0 = blockIdx.y * 128;
    const int b    = row0 / NN;

    const int r0 = tid >> 2;
    const int kk = (tid & 3) * 8;

    const unsigned short* ga0 = ehi + (size_t)(row0 + r0) * DD + kk;
    const unsigned short* ga1 = ga0 + (size_t)64 * DD;
    const unsigned short* gb0 = elo + (size_t)(row0 + r0) * DD + kk;
    const unsigned short* gb1 = gb0 + (size_t)64 * DD;
    const unsigned short* gc0 = wh  + (size_t)(col0 + r0) * DD + kk;
    const unsigned short* gc1 = gc0 + (size_t)64 * DD;
    const unsigned short* gd0 = wl  + (size_t)(col0 + r0) * DD + kk;
    const unsigned short* gd1 = gd0 + (size_t)64 * DD;

    char* lbase = (char*)&lds[0][0][0] + w * 1024;

    floatx4 acc[4][4];
    #pragma unroll
    for (int i = 0; i < 4; ++i)
        #pragma unroll
        for (int j = 0; j < 4; ++j)
            acc[i][j] = (floatx4){0.f, 0.f, 0.f, 0.f};

    for (int k0 = 0; k0 < DD; k0 += 32) {
        glds16(ga0 + k0, lbase + 0 * 4096);
        glds16(ga1 + k0, lbase + 1 * 4096);
        glds16(gb0 + k0, lbase + 2 * 4096);
        glds16(gb1 + k0, lbase + 3 * 4096);
        glds16(gc0 + k0, lbase + 4 * 4096);
        glds16(gc1 + k0, lbase + 5 * 4096);
        glds16(gd0 + k0, lbase + 6 * 4096);
        glds16(gd1 + k0, lbase + 7 * 4096);
        __syncthreads();

        short8 ah[4], al[4], bh[4], bl[4];
        #pragma unroll
        for (int i = 0; i < 4; ++i) {
            ah[i] = *(const short8*)&lds[0][wr * 64 + i * 16 + c15][quad * 8];
            al[i] = *(const short8*)&lds[1][wr * 64 + i * 16 + c15][quad * 8];
            bh[i] = *(const short8*)&lds[2][wc * 64 + i * 16 + c15][quad * 8];
            bl[i] = *(const short8*)&lds[3][wc * 64 + i * 16 + c15][quad * 8];
        }
        #pragma unroll
        for (int i = 0; i < 4; ++i)
            #pragma unroll
            for (int j = 0; j < 4; ++j) {
                acc[i][j] = __builtin_amdgcn_mfma_f32_16x16x32_bf16(ah[i], bh[j], acc[i][j], 0, 0, 0);
                acc[i][j] = __builtin_amdgcn_mfma_f32_16x16x32_bf16(al[i], bh[j], acc[i][j], 0, 0, 0);
                acc[i][j] = __builtin_amdgcn_mfma_f32_16x16x32_bf16(ah[i], bl[j], acc[i][j], 0, 0, 0);
            }
        __syncthreads();
    }

    float part[4][4];
    #pragma unroll
    for (int i = 0; i < 4; ++i)
        #pragma unroll
        for (int r = 0; r < 4; ++r) part[i][r] = 0.f;

    #pragma unroll
    for (int j = 0; j < 4; ++j) {
        int c = col0 + wc * 64 + j * 16 + c15;
        float qv = q[b * DD + c];
        float om = omega[c];
        #pragma unroll
        for (int i = 0; i < 4; ++i)
            #pragma unroll
            for (int r = 0; r < 4; ++r)
                part[i][r] += tanhf(acc[i][j][r] + qv) * om;
    }
    #pragma unroll
    for (int i = 0; i < 4; ++i)
        #pragma unroll
        for (int r = 0; r < 4; ++r) {
            float s = part[i][r];
            s += __shfl_xor(s, 1, 64);
            s += __shfl_xor(s, 2, 64);
            s += __shfl_xor(s, 4, 64);
            s += __shfl_xor(s, 8, 64);
            if (c15 == 0) red[wr * 64 + i * 16 + quad * 4 + r][wc] = s;
        }
    __syncthreads();
    if (tid < 128)
        sig_part[blockIdx.y * MM + row0 + tid] = red[tid][0] + red[tid][1];
}

// ---------------- cooperative tail: softmax -> u_part -> u -> A -> outputs
// 512 blocks x 256 threads (2 blocks/CU, co-resident under cooperative launch).
__global__ __launch_bounds__(256) void tail_coop(const float* __restrict__ sigp,
                                                 const float* __restrict__ imp,
                                                 const float* __restrict__ ej,
                                                 const float* __restrict__ Wv,
                                                 const float* __restrict__ Rlk,
                                                 float* __restrict__ a_ij,
                                                 float* __restrict__ u_part,
                                                 float* __restrict__ u,
                                                 float* __restrict__ Abuf,
                                                 float* __restrict__ out) {
    cg::grid_group grid = cg::this_grid();
    const int bid = blockIdx.x;
    const int tid = threadIdx.x;
    __shared__ float red[256];
    __shared__ float us[DD];

    // ---- Phase A: a_ij (64 blocks: 8 per b, each recomputes full stats)
    if (bid < 64) {
        int b = bid >> 3, slice = bid & 7;
        float sv[8];
        float m = -1e30f;
        #pragma unroll
        for (int p = 0; p < 8; ++p) {
            int n = p * 256 + tid;
            float s = 0.f;
            #pragma unroll
            for (int db = 0; db < 8; ++db) s += sigp[db * MM + b * NN + n];
            sv[p] = s;
            m = fmaxf(m, s);
        }
        red[tid] = m; __syncthreads();
        for (int off = 128; off; off >>= 1) {
            if (tid < off) red[tid] = fmaxf(red[tid], red[tid + off]);
            __syncthreads();
        }
        m = red[0]; __syncthreads();
        float sum = 0.f;
        #pragma unroll
        for (int p = 0; p < 8; ++p) sum += expf(sv[p] - m);
        red[tid] = sum; __syncthreads();
        for (int off = 128; off; off >>= 1) {
            if (tid < off) red[tid] += red[tid + off];
            __syncthreads();
        }
        float inv = 1.f / (red[0] + 1e-9f * expf(-m));
        int n = slice * 256 + tid;
        a_ij[b * NN + n] = imp[b * NN + n] * expf(sv[slice] - m) * inv;
    }
    grid.sync();

    // ---- Phase B: u partials (all 512 blocks, 32 rows each, disjoint writes)
    {
        int b = bid >> 6, nc = bid & 63;
        float4 acc = {0.f, 0.f, 0.f, 0.f};
        const float* base = ej + ((size_t)(b * NN + nc * 32)) * DD + tid * 4;
        const float* ap = a_ij + b * NN + nc * 32;
        #pragma unroll 4
        for (int n = 0; n < 32; ++n) {
            float a = ap[n];
            float4 v = *(const float4*)(base + (size_t)n * DD);
            acc.x += a * v.x; acc.y += a * v.y; acc.z += a * v.z; acc.w += a * v.w;
        }
        *(float4*)(u_part + ((size_t)nc * BB + b) * DD + tid * 4) = acc;
    }
    grid.sync();

    // ---- Phase C: reduce u_part over 64 slices (32 blocks)
    if (bid < 32) {
        int i = bid * 256 + tid;   // < 8192
        float s = 0.f;
        #pragma unroll 8
        for (int nc = 0; nc < 64; ++nc) s += u_part[(size_t)nc * BB * DD + i];
        u[i] = s;
    }
    grid.sync();

    // ---- Phase D: A = u @ Wv^T. Block: b = bid>>6, 16 d's; u[b] cached in LDS.
    {
        int b  = bid >> 6;
        int d0 = (bid & 63) * 16;
        #pragma unroll
        for (int e0 = 0; e0 < DD; e0 += 256) us[e0 + tid] = u[b * DD + e0 + tid];
        __syncthreads();
        int w = tid >> 6, lane = tid & 63;
        #pragma unroll
        for (int j = 0; j < 4; ++j) {
            int d = d0 + w * 4 + j;
            const float* wr = Wv + (size_t)d * DD;
            float s = 0.f;
            #pragma unroll
            for (int e0 = 0; e0 < DD; e0 += 256) {
                float4 wv = *(const float4*)&wr[e0 + lane * 4];
                float4 uv = *(const float4*)&us[e0 + lane * 4];
                s += wv.x * uv.x + wv.y * uv.y + wv.z * uv.z + wv.w * uv.w;
            }
            #pragma unroll
            for (int off = 32; off; off >>= 1) s += __shfl_down(s, off, 64);
            if (lane == 0) Abuf[b * DD + d] = s;
        }
    }
    grid.sync();

    // ---- Phase E: outputs. A_lk grid-stride (8 iters); A and A_l on blocks 0..31.
    {
        int base = bid * 256 + tid;
        #pragma unroll
        for (int it = 0; it < 8; ++it) {
            int i = base + it * 131072;    // < BB*LL*DD = 1048576
            int d = i & (DD - 1);
            int l = (i >> 10) & (LL - 1);
            int b = i >> 17;
            out[BB * DD + i] = Abuf[b * DD + d] * Rlk[l * DD + d];
        }
        if (base < BB * DD) {
            float a = Abuf[base];
            out[base] = a;
            out[BB * DD + BB * LL * DD + base] = a;
        }
    }
}

extern "C" void kernel_launch(void* const* d_in, const int* in_sizes, int n_in,
                              void* d_out, int out_size, void* d_ws, size_t ws_size,
                              hipStream_t stream) {
    const float* e_i   = (const float*)d_in[0];
    const float* e_j   = (const float*)d_in[1];
    const float* imp   = (const float*)d_in[2];
    const float* Rlk   = (const float*)d_in[3];
    const float* Wq    = (const float*)d_in[4];
    const float* Wk    = (const float*)d_in[5];
    const float* Wv    = (const float*)d_in[6];
    const float* omega = (const float*)d_in[7];
    float* out = (float*)d_out;
    float* ws  = (float*)d_ws;

    float* q    = ws;               // 8192 floats (doubles as Abuf after sigma)
    float* sigp = ws + 8192;        // 131072
    float* a_ij = ws + 139264;      // 16384
    float* u    = ws + 155648;      // 8192
    unsigned short* ehi = (unsigned short*)(ws + 172032);
    unsigned short* elo = ehi + (size_t)MM * DD;
    unsigned short* wh  = elo + (size_t)MM * DD;
    unsigned short* wl  = wh + (size_t)DD * DD;
    // u_part aliases wh/wl (dead after sigma): 64*8*1024 floats = 2 MB
    float* u_part = (float*)wh;
    float* Abuf   = q;              // q dead after sigma

    // 1) split e_j, split Wk, q = e_i @ Wq^T
    prep_kernel<<<10752, 256, 0, stream>>>(e_j, ehi, elo, Wk, wh, wl, e_i, Wq, q);

    // 2) sigma partials: bf16x3 MFMA GEMM (16x16x32, 128x128 tiles)
    sigma_mfma<<<dim3(MM / 128, DD / 128), 256, 0, stream>>>(ehi, elo, wh, wl, q, omega, sigp);

    // 3) everything else in one cooperative kernel (grid.sync between phases)
    void* args[] = {(void*)&sigp, (void*)&imp, (void*)&e_j, (void*)&Wv, (void*)&Rlk,
                    (void*)&a_ij, (void*)&u_part, (void*)&u, (void*)&Abuf, (void*)&out};
    hipLaunchCooperativeKernel((void*)tail_coop, dim3(512), dim3(256), args, 0, stream);
}

// Round 8
// 228.495 us; speedup vs baseline: 2.1843x; 2.1843x over previous
//
#include <hip/hip_runtime.h>
#include <hip/hip_bf16.h>
#include <math.h>

#define BB 8
#define NN 2048
#define DD 1024
#define LL 128
#define MM (BB*NN)   // 16384

typedef _Float16 half8 __attribute__((ext_vector_type(8)));
typedef _Float16 half4 __attribute__((ext_vector_type(4)));
typedef __attribute__((ext_vector_type(4))) float floatx4;

__device__ __forceinline__ void glds16(const void* g, void* l) {
    __builtin_amdgcn_global_load_lds(
        (const __attribute__((address_space(1))) unsigned int*)g,
        (__attribute__((address_space(3))) unsigned int*)l, 16, 0, 0);
}

// ---------------- fused preprocessing: e_j -> fp16, Wk -> fp16 hi/lo, q = e_i @ Wq^T
__global__ __launch_bounds__(256) void prep_kernel(const float* __restrict__ e_j,
                                                   _Float16* __restrict__ eh,
                                                   const float* __restrict__ Wk,
                                                   _Float16* __restrict__ wh,
                                                   _Float16* __restrict__ wl,
                                                   const float* __restrict__ e_i,
                                                   const float* __restrict__ Wq,
                                                   float* __restrict__ q) {
    int blk = blockIdx.x;
    int tid = threadIdx.x;
    if (blk < 8192) {
        // e_j -> fp16 (single, RNE): 8 elems/thread
        int i = blk * 256 + tid;
        const float4* xp = (const float4*)e_j + (size_t)i * 2;
        float4 v0 = xp[0], v1 = xp[1];
        half8 h;
        h[0] = (_Float16)v0.x; h[1] = (_Float16)v0.y;
        h[2] = (_Float16)v0.z; h[3] = (_Float16)v0.w;
        h[4] = (_Float16)v1.x; h[5] = (_Float16)v1.y;
        h[6] = (_Float16)v1.z; h[7] = (_Float16)v1.w;
        *(half8*)(eh + (size_t)i * 8) = h;
    } else if (blk < 8704) {
        // Wk -> fp16 hi + fp16 residual
        int i = (blk - 8192) * 256 + tid;
        const float4* xp = (const float4*)Wk + (size_t)i * 2;
        float4 v0 = xp[0], v1 = xp[1];
        float f[8] = {v0.x, v0.y, v0.z, v0.w, v1.x, v1.y, v1.z, v1.w};
        half8 hh, hl;
        #pragma unroll
        for (int e = 0; e < 8; ++e) {
            _Float16 hi = (_Float16)f[e];
            hh[e] = hi;
            hl[e] = (_Float16)(f[e] - (float)hi);
        }
        *(half8*)(wh + (size_t)i * 8) = hh;
        *(half8*)(wl + (size_t)i * 8) = hl;
    } else {
        int wid  = ((blk - 8704) * 256 + tid) >> 6;   // 0..8191
        int lane = tid & 63;
        int r = wid >> 10;
        int d = wid & (DD - 1);
        const float* x = e_i + (size_t)r * DD;
        const float* w = Wq + (size_t)d * DD;
        float s = 0.f;
        #pragma unroll
        for (int e0 = 0; e0 < DD; e0 += 256) {
            float4 xv = *(const float4*)&x[e0 + lane * 4];
            float4 wv = *(const float4*)&w[e0 + lane * 4];
            s += xv.x * wv.x + xv.y * wv.y + xv.z * wv.z + xv.w * wv.w;
        }
        #pragma unroll
        for (int off = 32; off; off >>= 1) s += __shfl_down(s, off, 64);
        if (lane == 0) q[wid] = s;
    }
}

// ---------------- heavy kernel: fp16 A x (fp16 hi/lo) B, 2 MFMA passes, fused epilogue
// Block 128x128, BK=32, 4 waves 2x2, per wave-k-iter: 32 MFMA / 12 ds_read_b128 / 6 glds16.
__global__ __launch_bounds__(256) void sigma_mfma(const _Float16* __restrict__ eh,
                                                  const _Float16* __restrict__ wh,
                                                  const _Float16* __restrict__ wl,
                                                  const float* __restrict__ q,
                                                  const float* __restrict__ omega,
                                                  float* __restrict__ sig_part)   // [8][MM]
{
    __shared__ _Float16 Ah[128][32];   // 8 KB
    __shared__ _Float16 Bh[128][32];   // 8 KB
    __shared__ _Float16 Bl[128][32];   // 8 KB
    __shared__ float red[128][2];

    const int tid  = threadIdx.x;
    const int lane = tid & 63;
    const int w    = tid >> 6;
    const int wr   = w >> 1, wc = w & 1;
    const int c15  = lane & 15, quad = lane >> 4;

    const int row0 = blockIdx.x * 128;
    const int col0 = blockIdx.y * 128;
    const int b    = row0 / NN;

    const int r0 = tid >> 2;            // 0..63
    const int ku = (tid & 3) * 8;       // k offset in halfs

    const _Float16* gA  = eh + (size_t)(row0 + r0) * DD + ku;
    const _Float16* gBh = wh + (size_t)(col0 + r0) * DD + ku;
    const _Float16* gBl = wl + (size_t)(col0 + r0) * DD + ku;

    char* dA  = (char*)&Ah[0][0] + w * 1024;
    char* dBh = (char*)&Bh[0][0] + w * 1024;
    char* dBl = (char*)&Bl[0][0] + w * 1024;

    floatx4 acc[4][4];
    #pragma unroll
    for (int i = 0; i < 4; ++i)
        #pragma unroll
        for (int j = 0; j < 4; ++j)
            acc[i][j] = (floatx4){0.f, 0.f, 0.f, 0.f};

    for (int k0 = 0; k0 < DD; k0 += 32) {
        glds16(gA  + k0,                     dA);
        glds16(gA  + (size_t)64 * DD + k0,   dA + 4096);
        glds16(gBh + k0,                     dBh);
        glds16(gBh + (size_t)64 * DD + k0,   dBh + 4096);
        glds16(gBl + k0,                     dBl);
        glds16(gBl + (size_t)64 * DD + k0,   dBl + 4096);
        __syncthreads();

        half8 a[4], bhf[4], blf[4];
        #pragma unroll
        for (int i = 0; i < 4; ++i) {
            a[i]   = *(const half8*)&Ah[wr * 64 + i * 16 + c15][quad * 8];
            bhf[i] = *(const half8*)&Bh[wc * 64 + i * 16 + c15][quad * 8];
            blf[i] = *(const half8*)&Bl[wc * 64 + i * 16 + c15][quad * 8];
        }
        #pragma unroll
        for (int i = 0; i < 4; ++i)
            #pragma unroll
            for (int j = 0; j < 4; ++j) {
                acc[i][j] = __builtin_amdgcn_mfma_f32_16x16x32_f16(a[i], bhf[j], acc[i][j], 0, 0, 0);
                acc[i][j] = __builtin_amdgcn_mfma_f32_16x16x32_f16(a[i], blf[j], acc[i][j], 0, 0, 0);
            }
        __syncthreads();
    }

    float part[4][4];
    #pragma unroll
    for (int i = 0; i < 4; ++i)
        #pragma unroll
        for (int r = 0; r < 4; ++r) part[i][r] = 0.f;

    #pragma unroll
    for (int j = 0; j < 4; ++j) {
        int c = col0 + wc * 64 + j * 16 + c15;
        float qv = q[b * DD + c];
        float om = omega[c];
        #pragma unroll
        for (int i = 0; i < 4; ++i)
            #pragma unroll
            for (int r = 0; r < 4; ++r)
                part[i][r] += tanhf(acc[i][j][r] + qv) * om;
    }
    #pragma unroll
    for (int i = 0; i < 4; ++i)
        #pragma unroll
        for (int r = 0; r < 4; ++r) {
            float s = part[i][r];
            s += __shfl_xor(s, 1, 64);
            s += __shfl_xor(s, 2, 64);
            s += __shfl_xor(s, 4, 64);
            s += __shfl_xor(s, 8, 64);
            if (c15 == 0) red[wr * 64 + i * 16 + quad * 4 + r][wc] = s;
        }
    __syncthreads();
    if (tid < 128)
        sig_part[blockIdx.y * MM + row0 + tid] = red[tid][0] + red[tid][1];
}

// ---------------- per-b softmax-style weights (64 blocks: 8 per b, full stats each)
__global__ __launch_bounds__(256) void softmax_k(const float* __restrict__ sig_part,
                                                 const float* __restrict__ imp,
                                                 float* __restrict__ a_ij) {
    int b = blockIdx.x >> 3, slice = blockIdx.x & 7;
    int tid = threadIdx.x;
    __shared__ float red[256];
    float sv[8];
    float m = -1e30f;
    #pragma unroll
    for (int p = 0; p < 8; ++p) {
        int n = p * 256 + tid;
        float s = 0.f;
        #pragma unroll
        for (int db = 0; db < 8; ++db) s += sig_part[db * MM + b * NN + n];
        sv[p] = s;
        m = fmaxf(m, s);
    }
    red[tid] = m; __syncthreads();
    for (int off = 128; off; off >>= 1) {
        if (tid < off) red[tid] = fmaxf(red[tid], red[tid + off]);
        __syncthreads();
    }
    m = red[0]; __syncthreads();
    float sum = 0.f;
    #pragma unroll
    for (int p = 0; p < 8; ++p) sum += expf(sv[p] - m);
    red[tid] = sum; __syncthreads();
    for (int off = 128; off; off >>= 1) {
        if (tid < off) red[tid] += red[tid + off];
        __syncthreads();
    }
    float inv = 1.f / (red[0] + 1e-9f * expf(-m));
    int n = slice * 256 + tid;
    a_ij[b * NN + n] = imp[b * NN + n] * expf(sv[slice] - m) * inv;
}

// ---------------- u partials from fp16 e_j: 1024 blocks, disjoint writes
__global__ __launch_bounds__(256) void u_kernel(const float* __restrict__ a_ij,
                                                const _Float16* __restrict__ eh,
                                                float* __restrict__ u_part) {
    int b = blockIdx.x >> 7, nc = blockIdx.x & 127;
    int t = threadIdx.x;
    float4 acc = {0.f, 0.f, 0.f, 0.f};
    const _Float16* base = eh + ((size_t)(b * NN + nc * 16)) * DD + t * 4;
    const float* ap = a_ij + b * NN + nc * 16;
    #pragma unroll
    for (int n = 0; n < 16; ++n) {
        float a = ap[n];
        half4 v = *(const half4*)(base + (size_t)n * DD);
        acc.x += a * (float)v[0]; acc.y += a * (float)v[1];
        acc.z += a * (float)v[2]; acc.w += a * (float)v[3];
    }
    *(float4*)(u_part + ((size_t)nc * BB + b) * DD + t * 4) = acc;
}

// ---------------- u[b,e] = sum over 128 partials
__global__ __launch_bounds__(256) void ureduce(const float* __restrict__ u_part,
                                               float* __restrict__ u) {
    int i = blockIdx.x * 256 + threadIdx.x;   // < 8192
    float s = 0.f;
    #pragma unroll 8
    for (int nc = 0; nc < 128; ++nc) s += u_part[(size_t)nc * BB * DD + i];
    u[i] = s;
}

// ---------------- A = u @ Wv^T
__global__ __launch_bounds__(256) void rowdot_A(const float* __restrict__ X,
                                                const float* __restrict__ W,
                                                float* __restrict__ out) {
    int wid  = (blockIdx.x * blockDim.x + threadIdx.x) >> 6;
    int lane = threadIdx.x & 63;
    int r = wid >> 10;
    int d = wid & (DD - 1);
    const float* x = X + (size_t)r * DD;
    const float* w = W + (size_t)d * DD;
    float s = 0.f;
    #pragma unroll
    for (int e0 = 0; e0 < DD; e0 += 256) {
        float4 xv = *(const float4*)&x[e0 + lane * 4];
        float4 wv = *(const float4*)&w[e0 + lane * 4];
        s += xv.x * wv.x + xv.y * wv.y + xv.z * wv.z + xv.w * wv.w;
    }
    #pragma unroll
    for (int off = 32; off; off >>= 1) s += __shfl_down(s, off, 64);
    if (lane == 0) out[wid] = s;
}

// ---------------- outputs: A, A_lk = A*R, A_l = A
__global__ __launch_bounds__(256) void out_kernel(const float* __restrict__ A,
                                                  const float* __restrict__ Rlk,
                                                  float* __restrict__ out) {
    int i = blockIdx.x * 256 + threadIdx.x;
    int d = i & (DD - 1);
    int l = (i >> 10) & (LL - 1);
    int b = i >> 17;
    out[BB * DD + i] = A[b * DD + d] * Rlk[l * DD + d];
    if (i < BB * DD) {
        out[i] = A[i];
        out[BB * DD + BB * LL * DD + i] = A[i];
    }
}

extern "C" void kernel_launch(void* const* d_in, const int* in_sizes, int n_in,
                              void* d_out, int out_size, void* d_ws, size_t ws_size,
                              hipStream_t stream) {
    const float* e_i   = (const float*)d_in[0];
    const float* e_j   = (const float*)d_in[1];
    const float* imp   = (const float*)d_in[2];
    const float* Rlk   = (const float*)d_in[3];
    const float* Wq    = (const float*)d_in[4];
    const float* Wk    = (const float*)d_in[5];
    const float* Wv    = (const float*)d_in[6];
    const float* omega = (const float*)d_in[7];
    float* out = (float*)d_out;
    float* ws  = (float*)d_ws;

    float* q    = ws;               // 8192
    float* sigp = ws + 8192;        // 131072
    float* a_ij = ws + 139264;      // 16384
    float* u    = ws + 155648;      // 8192
    _Float16* eh = (_Float16*)(ws + 172032);      // MM*DD halfs = 32 MB
    _Float16* wh = eh + (size_t)MM * DD;          // 2 MB
    _Float16* wl = wh + (size_t)DD * DD;          // 2 MB
    // u_part aliases wh/wl (dead after sigma): 128*8*1024 floats = 4 MB exactly
    float* u_part = (float*)wh;

    // 1) e_j -> fp16, Wk -> fp16 hi/lo, q = e_i @ Wq^T
    prep_kernel<<<10752, 256, 0, stream>>>(e_j, eh, Wk, wh, wl, e_i, Wq, q);

    // 2) sigma partials: fp16 2-pass MFMA GEMM with fused tanh-omega reduction
    sigma_mfma<<<dim3(MM / 128, DD / 128), 256, 0, stream>>>(eh, wh, wl, q, omega, sigp);

    // 3) a_ij
    softmax_k<<<64, 256, 0, stream>>>(sigp, imp, a_ij);

    // 4) u partials (no atomics) from fp16 e_j, then reduce
    u_kernel<<<1024, 256, 0, stream>>>(a_ij, eh, u_part);
    ureduce<<<32, 256, 0, stream>>>(u_part, u);

    // 5) A = u @ Wv^T  (reuse a_ij head as Abuf)
    rowdot_A<<<2048, 256, 0, stream>>>(u, Wv, a_ij);

    // 6) outputs
    out_kernel<<<(BB * LL * DD) / 256, 256, 0, stream>>>(a_ij, Rlk, out);
}

// Round 9
// 209.667 us; speedup vs baseline: 2.3804x; 1.0898x over previous
//
#include <hip/hip_runtime.h>
#include <hip/hip_bf16.h>
#include <math.h>

#define BB 8
#define NN 2048
#define DD 1024
#define LL 128
#define MM (BB*NN)   // 16384

typedef _Float16 half8 __attribute__((ext_vector_type(8)));
typedef _Float16 half4 __attribute__((ext_vector_type(4)));
typedef __attribute__((ext_vector_type(4))) float floatx4;

__device__ __forceinline__ void glds16(const void* g, void* l) {
    __builtin_amdgcn_global_load_lds(
        (const __attribute__((address_space(1))) unsigned int*)g,
        (__attribute__((address_space(3))) unsigned int*)l, 16, 0, 0);
}

// ---------------- fused preprocessing: e_j -> fp16, Wk -> fp16, q = e_i @ Wq^T
// blocks [0,8192): e_j; [8192,8704): Wk; [8704,8960): q (Wq read ONCE, e_i in LDS)
__global__ __launch_bounds__(256) void prep_kernel(const float* __restrict__ e_j,
                                                   _Float16* __restrict__ eh,
                                                   const float* __restrict__ Wk,
                                                   _Float16* __restrict__ wh,
                                                   const float* __restrict__ e_i,
                                                   const float* __restrict__ Wq,
                                                   float* __restrict__ q) {
    __shared__ float us[BB][DD];   // 32 KB, used only by the q branch
    int blk = blockIdx.x;
    int tid = threadIdx.x;
    if (blk < 8192) {
        int i = blk * 256 + tid;
        const float4* xp = (const float4*)e_j + (size_t)i * 2;
        float4 v0 = xp[0], v1 = xp[1];
        half8 h;
        h[0] = (_Float16)v0.x; h[1] = (_Float16)v0.y;
        h[2] = (_Float16)v0.z; h[3] = (_Float16)v0.w;
        h[4] = (_Float16)v1.x; h[5] = (_Float16)v1.y;
        h[6] = (_Float16)v1.z; h[7] = (_Float16)v1.w;
        *(half8*)(eh + (size_t)i * 8) = h;
    } else if (blk < 8704) {
        int i = (blk - 8192) * 256 + tid;
        const float4* xp = (const float4*)Wk + (size_t)i * 2;
        float4 v0 = xp[0], v1 = xp[1];
        half8 h;
        h[0] = (_Float16)v0.x; h[1] = (_Float16)v0.y;
        h[2] = (_Float16)v0.z; h[3] = (_Float16)v0.w;
        h[4] = (_Float16)v1.x; h[5] = (_Float16)v1.y;
        h[6] = (_Float16)v1.z; h[7] = (_Float16)v1.w;
        *(half8*)(wh + (size_t)i * 8) = h;
    } else {
        // q[r,d] for d = (blk-8704)*4 + wave, all r at once; Wq row read once.
        for (int i = tid; i < BB * DD / 4; i += 256)
            ((float4*)&us[0][0])[i] = ((const float4*)e_i)[i];
        __syncthreads();
        int w = tid >> 6, lane = tid & 63;
        int d = (blk - 8704) * 4 + w;
        float acc[8] = {0.f, 0.f, 0.f, 0.f, 0.f, 0.f, 0.f, 0.f};
        for (int e0 = 0; e0 < DD; e0 += 256) {
            float4 wv = *(const float4*)&Wq[(size_t)d * DD + e0 + lane * 4];
            #pragma unroll
            for (int r = 0; r < 8; ++r) {
                float4 uv = *(const float4*)&us[r][e0 + lane * 4];
                acc[r] += wv.x * uv.x + wv.y * uv.y + wv.z * uv.z + wv.w * uv.w;
            }
        }
        #pragma unroll
        for (int r = 0; r < 8; ++r) {
            float s = acc[r];
            #pragma unroll
            for (int off = 32; off; off >>= 1) s += __shfl_down(s, off, 64);
            if (lane == 0) q[r * DD + d] = s;
        }
    }
}

// ---------------- heavy kernel: single-pass fp16 MFMA GEMM (m97 structure) + epilogue
// 128x128 tile, BK=32, 4 waves 2x2; per wave-iter: 16 MFMA / 8 ds_read_b128 / 4 glds16.
__global__ __launch_bounds__(256) void sigma_mfma(const _Float16* __restrict__ eh,
                                                  const _Float16* __restrict__ wh,
                                                  const float* __restrict__ q,
                                                  const float* __restrict__ omega,
                                                  float* __restrict__ sig_part)   // [8][MM]
{
    __shared__ _Float16 Ah[128][32];   // 8 KB
    __shared__ _Float16 Bh[128][32];   // 8 KB
    __shared__ float red[128][2];

    const int tid  = threadIdx.x;
    const int lane = tid & 63;
    const int w    = tid >> 6;
    const int wr   = w >> 1, wc = w & 1;
    const int c15  = lane & 15, quad = lane >> 4;

    const int row0 = blockIdx.x * 128;
    const int col0 = blockIdx.y * 128;
    const int b    = row0 / NN;

    const int r0 = tid >> 2;            // 0..63
    const int ku = (tid & 3) * 8;       // k offset in halfs

    const _Float16* gA = eh + (size_t)(row0 + r0) * DD + ku;
    const _Float16* gB = wh + (size_t)(col0 + r0) * DD + ku;

    char* dA = (char*)&Ah[0][0] + w * 1024;
    char* dB = (char*)&Bh[0][0] + w * 1024;

    floatx4 acc[4][4];
    #pragma unroll
    for (int i = 0; i < 4; ++i)
        #pragma unroll
        for (int j = 0; j < 4; ++j)
            acc[i][j] = (floatx4){0.f, 0.f, 0.f, 0.f};

    for (int k0 = 0; k0 < DD; k0 += 32) {
        glds16(gA + k0,                   dA);
        glds16(gA + (size_t)64 * DD + k0, dA + 4096);
        glds16(gB + k0,                   dB);
        glds16(gB + (size_t)64 * DD + k0, dB + 4096);
        __syncthreads();

        half8 a[4], bf[4];
        #pragma unroll
        for (int i = 0; i < 4; ++i) {
            a[i]  = *(const half8*)&Ah[wr * 64 + i * 16 + c15][quad * 8];
            bf[i] = *(const half8*)&Bh[wc * 64 + i * 16 + c15][quad * 8];
        }
        #pragma unroll
        for (int i = 0; i < 4; ++i)
            #pragma unroll
            for (int j = 0; j < 4; ++j)
                acc[i][j] = __builtin_amdgcn_mfma_f32_16x16x32_f16(a[i], bf[j], acc[i][j], 0, 0, 0);
        __syncthreads();
    }

    float part[4][4];
    #pragma unroll
    for (int i = 0; i < 4; ++i)
        #pragma unroll
        for (int r = 0; r < 4; ++r) part[i][r] = 0.f;

    #pragma unroll
    for (int j = 0; j < 4; ++j) {
        int c = col0 + wc * 64 + j * 16 + c15;
        float qv = q[b * DD + c];
        float om = omega[c];
        #pragma unroll
        for (int i = 0; i < 4; ++i)
            #pragma unroll
            for (int r = 0; r < 4; ++r)
                part[i][r] += tanhf(acc[i][j][r] + qv) * om;
    }
    #pragma unroll
    for (int i = 0; i < 4; ++i)
        #pragma unroll
        for (int r = 0; r < 4; ++r) {
            float s = part[i][r];
            s += __shfl_xor(s, 1, 64);
            s += __shfl_xor(s, 2, 64);
            s += __shfl_xor(s, 4, 64);
            s += __shfl_xor(s, 8, 64);
            if (c15 == 0) red[wr * 64 + i * 16 + quad * 4 + r][wc] = s;
        }
    __syncthreads();
    if (tid < 128)
        sig_part[blockIdx.y * MM + row0 + tid] = red[tid][0] + red[tid][1];
}

// ---------------- per-b softmax-style weights (64 blocks: 8 per b, full stats each)
__global__ __launch_bounds__(256) void softmax_k(const float* __restrict__ sig_part,
                                                 const float* __restrict__ imp,
                                                 float* __restrict__ a_ij) {
    int b = blockIdx.x >> 3, slice = blockIdx.x & 7;
    int tid = threadIdx.x;
    __shared__ float red[256];
    float sv[8];
    float m = -1e30f;
    #pragma unroll
    for (int p = 0; p < 8; ++p) {
        int n = p * 256 + tid;
        float s = 0.f;
        #pragma unroll
        for (int db = 0; db < 8; ++db) s += sig_part[db * MM + b * NN + n];
        sv[p] = s;
        m = fmaxf(m, s);
    }
    red[tid] = m; __syncthreads();
    for (int off = 128; off; off >>= 1) {
        if (tid < off) red[tid] = fmaxf(red[tid], red[tid + off]);
        __syncthreads();
    }
    m = red[0]; __syncthreads();
    float sum = 0.f;
    #pragma unroll
    for (int p = 0; p < 8; ++p) sum += expf(sv[p] - m);
    red[tid] = sum; __syncthreads();
    for (int off = 128; off; off >>= 1) {
        if (tid < off) red[tid] += red[tid + off];
        __syncthreads();
    }
    float inv = 1.f / (red[0] + 1e-9f * expf(-m));
    int n = slice * 256 + tid;
    a_ij[b * NN + n] = imp[b * NN + n] * expf(sv[slice] - m) * inv;
}

// ---------------- u partials from fp16 e_j: 1024 blocks, disjoint writes
__global__ __launch_bounds__(256) void u_kernel(const float* __restrict__ a_ij,
                                                const _Float16* __restrict__ eh,
                                                float* __restrict__ u_part) {
    int b = blockIdx.x >> 7, nc = blockIdx.x & 127;
    int t = threadIdx.x;
    float4 acc = {0.f, 0.f, 0.f, 0.f};
    const _Float16* base = eh + ((size_t)(b * NN + nc * 16)) * DD + t * 4;
    const float* ap = a_ij + b * NN + nc * 16;
    #pragma unroll
    for (int n = 0; n < 16; ++n) {
        float a = ap[n];
        half4 v = *(const half4*)(base + (size_t)n * DD);
        acc.x += a * (float)v[0]; acc.y += a * (float)v[1];
        acc.z += a * (float)v[2]; acc.w += a * (float)v[3];
    }
    *(float4*)(u_part + ((size_t)nc * BB + b) * DD + t * 4) = acc;
}

// ---------------- u[b,e] = sum over 128 partials
__global__ __launch_bounds__(256) void ureduce(const float* __restrict__ u_part,
                                               float* __restrict__ u) {
    int i = blockIdx.x * 256 + threadIdx.x;   // < 8192
    float s = 0.f;
    #pragma unroll 8
    for (int nc = 0; nc < 128; ++nc) s += u_part[(size_t)nc * BB * DD + i];
    u[i] = s;
}

// ---------------- A = X @ W^T with X cached in LDS; W read once (256 blocks)
__global__ __launch_bounds__(256) void rowdot8(const float* __restrict__ X,
                                               const float* __restrict__ W,
                                               float* __restrict__ out) {
    __shared__ float us[BB][DD];
    int tid = threadIdx.x;
    for (int i = tid; i < BB * DD / 4; i += 256)
        ((float4*)&us[0][0])[i] = ((const float4*)X)[i];
    __syncthreads();
    int w = tid >> 6, lane = tid & 63;
    int d = blockIdx.x * 4 + w;
    float acc[8] = {0.f, 0.f, 0.f, 0.f, 0.f, 0.f, 0.f, 0.f};
    for (int e0 = 0; e0 < DD; e0 += 256) {
        float4 wv = *(const float4*)&W[(size_t)d * DD + e0 + lane * 4];
        #pragma unroll
        for (int r = 0; r < 8; ++r) {
            float4 uv = *(const float4*)&us[r][e0 + lane * 4];
            acc[r] += wv.x * uv.x + wv.y * uv.y + wv.z * uv.z + wv.w * uv.w;
        }
    }
    #pragma unroll
    for (int r = 0; r < 8; ++r) {
        float s = acc[r];
        #pragma unroll
        for (int off = 32; off; off >>= 1) s += __shfl_down(s, off, 64);
        if (lane == 0) out[r * DD + d] = s;
    }
}

// ---------------- outputs: A, A_lk = A*R, A_l = A
__global__ __launch_bounds__(256) void out_kernel(const float* __restrict__ A,
                                                  const float* __restrict__ Rlk,
                                                  float* __restrict__ out) {
    int i = blockIdx.x * 256 + threadIdx.x;
    int d = i & (DD - 1);
    int l = (i >> 10) & (LL - 1);
    int b = i >> 17;
    out[BB * DD + i] = A[b * DD + d] * Rlk[l * DD + d];
    if (i < BB * DD) {
        out[i] = A[i];
        out[BB * DD + BB * LL * DD + i] = A[i];
    }
}

extern "C" void kernel_launch(void* const* d_in, const int* in_sizes, int n_in,
                              void* d_out, int out_size, void* d_ws, size_t ws_size,
                              hipStream_t stream) {
    const float* e_i   = (const float*)d_in[0];
    const float* e_j   = (const float*)d_in[1];
    const float* imp   = (const float*)d_in[2];
    const float* Rlk   = (const float*)d_in[3];
    const float* Wq    = (const float*)d_in[4];
    const float* Wk    = (const float*)d_in[5];
    const float* Wv    = (const float*)d_in[6];
    const float* omega = (const float*)d_in[7];
    float* out = (float*)d_out;
    float* ws  = (float*)d_ws;

    float* q    = ws;               // 8192
    float* sigp = ws + 8192;        // 131072
    float* a_ij = ws + 139264;      // 16384 (head reused as Abuf)
    float* u    = ws + 155648;      // 8192
    _Float16* eh = (_Float16*)(ws + 172032);      // MM*DD halfs = 32 MB
    _Float16* wh = eh + (size_t)MM * DD;          // 2 MB
    float* u_part = (float*)(wh + (size_t)DD * DD);  // 4 MB

    // 1) e_j -> fp16, Wk -> fp16, q = e_i @ Wq^T (Wq read once)
    prep_kernel<<<8960, 256, 0, stream>>>(e_j, eh, Wk, wh, e_i, Wq, q);

    // 2) sigma partials: single-pass fp16 MFMA GEMM with fused tanh-omega reduction
    sigma_mfma<<<dim3(MM / 128, DD / 128), 256, 0, stream>>>(eh, wh, q, omega, sigp);

    // 3) a_ij
    softmax_k<<<64, 256, 0, stream>>>(sigp, imp, a_ij);

    // 4) u partials (no atomics) from fp16 e_j, then reduce
    u_kernel<<<1024, 256, 0, stream>>>(a_ij, eh, u_part);
    ureduce<<<32, 256, 0, stream>>>(u_part, u);

    // 5) A = u @ Wv^T (Wv read once; Abuf = a_ij head)
    rowdot8<<<256, 256, 0, stream>>>(u, Wv, a_ij);

    // 6) outputs
    out_kernel<<<(BB * LL * DD) / 256, 256, 0, stream>>>(a_ij, Rlk, out);
}